// Round 17
// baseline (23.382 us; speedup 1.0000x reference)
//
#include <hip/hip_runtime.h>
#include <math.h>

// ConvCaps EM-routing, MI355X — 8-slice EM: 256-thread block (4 waves) per
// group, 8 lanes per output capsule, 4 c's per lane => 9216 waves (2x TLP).
// All cross-lane reduces full-rate VALU (DPP row_ror:8 + permlane swaps).
//
// Algebra: vv[n,ci,co,k] = Sv(n,ci,co>>1) * Wsum(sp=n%36,ci,co,k&3), so EM
// runs on a 32x32x4 table. Wave wv owns o = wv*8+(lane&7); s = lane>>3 owns
// c = s*4..s*4+3.

#define EPSF 1e-8f

typedef float f2 __attribute__((ext_vector_type(2)));
typedef unsigned u32x2 __attribute__((ext_vector_type(2)));

__device__ __forceinline__ float rcpf(float x) { return __builtin_amdgcn_rcpf(x); }

// DPP helpers (full-rate VALU lane exchange)
__device__ __forceinline__ float dpp_ror8(float x) {     // lane l <- l^8 (row_ror:8)
    return __int_as_float(__builtin_amdgcn_update_dpp(
        0, __float_as_int(x), 0x128, 0xF, 0xF, true));
}
__device__ __forceinline__ float dpp_xor1(float x) {     // quad_perm [1,0,3,2]
    return __int_as_float(__builtin_amdgcn_update_dpp(
        0, __float_as_int(x), 0xB1, 0xF, 0xF, true));
}
__device__ __forceinline__ float dpp_xor2(float x) {     // quad_perm [2,3,0,1]
    return __int_as_float(__builtin_amdgcn_update_dpp(
        0, __float_as_int(x), 0x4E, 0xF, 0xF, true));
}
__device__ __forceinline__ float dpp_mirror7(float x) {  // ROW_HALF_MIRROR: l <- l^7 in 8-group
    return __int_as_float(__builtin_amdgcn_update_dpp(
        0, __float_as_int(x), 0x141, 0xF, 0xF, true));
}

// sum over the 8 lanes {l ^ {8,16,32}-span}; result in all 8 lanes.
__device__ __forceinline__ float reduce8(float x) {
    x += dpp_ror8(x);
#if __has_builtin(__builtin_amdgcn_permlane16_swap) && __has_builtin(__builtin_amdgcn_permlane32_swap)
    unsigned xu = __float_as_uint(x);
    u32x2 p = __builtin_amdgcn_permlane16_swap(xu, xu, false, false);
    float s = __uint_as_float(p.x) + __uint_as_float(p.y);
    unsigned su = __float_as_uint(s);
    u32x2 q = __builtin_amdgcn_permlane32_swap(su, su, false, false);
    return __uint_as_float(q.x) + __uint_as_float(q.y);
#else
    x += __shfl_xor(x, 16);
    x += __shfl_xor(x, 32);
    return x;
#endif
}

// ---- pre: box-filtered channel sums (S,A) + Wsum[36][32][32][4] (R7) ----
__global__ __launch_bounds__(256) void pre_kernel(
        const float* __restrict__ x, const float* __restrict__ a,
        const float* __restrict__ w,
        float* __restrict__ S, float* __restrict__ A, float* __restrict__ Wsum) {
    int bid = blockIdx.x;
    if (bid < 1088) {
        __shared__ float plane[6272];
        __shared__ float bsum[196];
        const int t = threadIdx.x;
        const float* src = (bid < 1024) ? (x + (size_t)bid * 6272)
                                        : (a + (size_t)(bid - 1024) * 6272);
        for (int k = t; k < 1568; k += 256)
            *(float4*)&plane[k * 4] = *(const float4*)(src + k * 4);
        __syncthreads();
        if (t < 196) {
            float s = 0.f;
#pragma unroll
            for (int c = 0; c < 32; ++c) s += plane[c * 196 + t];
            bsum[t] = s;
        }
        __syncthreads();
        if (t < 36) {
            int oy = t / 6, ox = t - oy * 6;
            const float* q = &bsum[oy * 28 + ox * 2];
            float s = (q[0] + q[1] + q[2]) + (q[14] + q[15] + q[16])
                    + (q[28] + q[29] + q[30]);
            s *= (1.0f / 9.0f);
            if (bid < 1024) S[bid * 36 + t] = s;
            else            A[(bid - 1024) * 36 + t] = s;
        }
    } else {
        int wi = (bid - 1088) * 256 + threadIdx.x;   // 147456 Wsum entries
        int sp = wi >> 12;
        int rr = wi & 4095;
        int ci = rr >> 7, co = (rr >> 2) & 31, j = rr & 3;
        int B = sp * 32 + ci;
        int cc = B / 36;
        int rem = B - cc * 36;
        int wbase = cc * 18432 + (rem / 6) * 3072 + (rem % 6) * 512 + co * 16 + j;
        Wsum[wi] = w[wbase] + w[wbase + 4] + w[wbase + 8] + w[wbase + 12];
    }
}

// ---- EM: one 256-thread block (4 waves) per routing group ----
__global__ __launch_bounds__(256, 6) void em_kernel(
        const float* __restrict__ bu, const float* __restrict__ ba,
        const float* __restrict__ S, const float* __restrict__ A,
        const float* __restrict__ Wsum, float* __restrict__ out) {
    __shared__ float lgb[33 * 32];      // [c][o], stride 33 (only LDS use)

    const int t = threadIdx.x;
    const int wv = t >> 6;
    const int lane = t & 63;
    const int o = wv * 8 + (lane & 7);  // owned output capsule
    const int s = lane >> 3;            // c-slice (0..7)
    const int c0 = s * 4;
    const int n = blockIdx.x;
    const int bq = n / 36;
    const int sp = n - bq * 36;

    // ---- setup: 12 independent gathers (S/A/Wsum are L2-hot), no barrier
    const int hc = o >> 1;
    f2 V2[4][2];
    float avr[4], r[4];
    const float* Wn = Wsum + sp * 4096;
#pragma unroll
    for (int cl = 0; cl < 4; ++cl) {
        int c = c0 + cl;
        int B = sp * 32 + c;
        int cc = B / 36;
        int rem = B - cc * 36;
        int off = cc * 576 + (rem / 6) * 96 + (rem % 6) * 16 + hc;
        int hi = off / 1152;
        int lo = off - hi * 1152;
        float sv = S[(bq * 16 + hi) * 36 + lo % 36];
        float4 w4 = *(const float4*)(Wn + c * 128 + o * 4);
        V2[cl][0] = (f2){sv * w4.x, sv * w4.y};
        V2[cl][1] = (f2){sv * w4.z, sv * w4.w};
        avr[cl] = A[bq * 36 + (32 * sp + c) % 36];
        r[cl] = 0.03125f;
    }
    const float bu16 = 16.0f * bu[o];
    const float ba_o = ba[o];
    f2 mu2[2], q2[2];
    float aout = 0.f;
    const float lambdas[3] = {5.0e-4f, 9.75e-4f, 1.42625e-3f};

    for (int it = 0; it < 3; ++it) {
        // ---- pass 1: rp, rs, mu (8-lane reduce, all-VALU) ----
        float rp[4];
#pragma unroll
        for (int cl = 0; cl < 4; ++cl) rp[cl] = r[cl] * avr[cl] + EPSF;
        float rs = (rp[0] + rp[1]) + (rp[2] + rp[3]);
        rs = reduce8(rs);
        float rinv = rcpf(rs);
#pragma unroll
        for (int p = 0; p < 2; ++p) {
            f2 a0 = rp[0] * V2[0][p] + rp[1] * V2[1][p];
            f2 a1 = rp[2] * V2[2][p] + rp[3] * V2[3][p];
            f2 m = a0 + a1;
            m.x = reduce8(m.x);
            m.y = reduce8(m.y);
            mu2[p] = m * rinv;
        }
        // ---- pass 2: sig (non-negative), single fused log ----
        float L;
        {
            f2 sgv[2];
#pragma unroll
            for (int p = 0; p < 2; ++p) {
                f2 d0 = V2[0][p] - mu2[p];
                f2 d1 = V2[1][p] - mu2[p];
                f2 d2 = V2[2][p] - mu2[p];
                f2 d3 = V2[3][p] - mu2[p];
                f2 sg = ((d0 * d0) * rp[0] + (d1 * d1) * rp[1])
                      + ((d2 * d2) * rp[2] + (d3 * d3) * rp[3]);
                sg.x = reduce8(sg.x);
                sg.y = reduce8(sg.y);
                sgv[p] = sg * rinv + EPSF;
                q2[p] = (f2){2.0f * rcpf(sgv[p].x), 2.0f * rcpf(sgv[p].y)};
            }
            L = __logf((sgv[0].x * sgv[0].y) * (sgv[1].x * sgv[1].y));
        }
        float cost = (bu16 + 2.0f * L) * rs;
        float z = lambdas[it] * (ba_o - cost);

        if (it < 2) {
            // log-sigmoid identity: log(aout) = -log(1 + e^-z)
            float la = -__logf(1.0f + __expf(-z));
            float T = la - 2.0f * L;
#pragma unroll
            for (int cl = 0; cl < 4; ++cl) {
                f2 d0 = V2[cl][0] - mu2[0];
                f2 d1 = V2[cl][1] - mu2[1];
                f2 s2 = (d0 * d0) * q2[0] + (d1 * d1) * q2[1];
                lgb[(c0 + cl) * 33 + o] = T - (s2.x + s2.y);
            }
            __syncthreads();
            // transposed softmax: 256 lanes, lane = (c-row cT, o-quarter q)
            {
                int cT = t >> 3, q = t & 7;
                float* rowp = &lgb[cT * 33 + q * 4];
                float4 u = *(float4*)(rowp);
                float m = fmaxf(fmaxf(u.x, u.y), fmaxf(u.z, u.w));
                m = fmaxf(m, dpp_xor1(m));
                m = fmaxf(m, dpp_xor2(m));
                m = fmaxf(m, dpp_mirror7(m));   // completes 8-lane butterfly
                u.x = __expf(u.x - m); u.y = __expf(u.y - m);
                u.z = __expf(u.z - m); u.w = __expf(u.w - m);
                float ssum = (u.x + u.y) + (u.z + u.w);
                ssum += dpp_xor1(ssum);
                ssum += dpp_xor2(ssum);
                ssum += dpp_mirror7(ssum);
                float inv = rcpf(ssum);
                u.x *= inv; u.y *= inv; u.z *= inv; u.w *= inv;
                *(float4*)(rowp) = u;
            }
            __syncthreads();
#pragma unroll
            for (int cl = 0; cl < 4; ++cl)
                r[cl] = lgb[(c0 + cl) * 33 + o];
        } else {
            aout = rcpf(1.0f + __expf(-z));
        }
    }

    // outputs: mu expanded to 16 k (k>>2 drops out); 8 s-lanes hold identical
    // mu for their o — lanes s<4 each write one float4 quarter of the 16-k row.
    float4 val = {mu2[0].x, mu2[0].y, mu2[1].x, mu2[1].y};
    float4* po = (float4*)(out + n * 512 + o * 16);
    if (s < 4) po[s] = val;
    if (s == 0) out[1179648 + n * 32 + o] = aout;
}

extern "C" void kernel_launch(void* const* d_in, const int* in_sizes, int n_in,
                              void* d_out, int out_size, void* d_ws, size_t ws_size,
                              hipStream_t stream) {
    const float* x = (const float*)d_in[0];
    const float* a = (const float*)d_in[1];
    const float* w = (const float*)d_in[2];
    const float* bu = (const float*)d_in[3];
    const float* ba = (const float*)d_in[4];
    float* out = (float*)d_out;

    float* S    = (float*)d_ws;          // 36864
    float* A    = S + 36864;             // 2304
    float* Wsum = A + 2304;              // 147456

    pre_kernel<<<1088 + 576, 256, 0, stream>>>(x, a, w, S, A, Wsum);
    em_kernel<<<2304, 256, 0, stream>>>(bu, ba, S, A, Wsum, out);
}